// Round 6
// baseline (435.161 us; speedup 1.0000x reference)
//
#include <hip/hip_runtime.h>

typedef __bf16 bf16;
typedef __bf16 bf16x4 __attribute__((ext_vector_type(4)));
typedef __bf16 bf16x8 __attribute__((ext_vector_type(8)));
typedef float  f32x4  __attribute__((ext_vector_type(4)));
typedef unsigned int uint32;

#define BT 32

// ---- bf16 workspace layout (element offsets) ----
#define N_E0 (339*128)
#define N_E1 (5825*128)
#define N_E2 (64*128)
#define N_W1 (256*128)
#define N_W2 (256*768)
#define N_F1 (256*256)
#define N_F2 256
#define O_E0 0
#define O_E1 (O_E0+N_E0)
#define O_E2 (O_E1+N_E1)
#define O_W1 (O_E2+N_E2)
#define O_W2 (O_W1+N_W1)   // holds w2 TRANSPOSED: [d][m*256+c]
#define O_F1 (O_W2+N_W2)
#define O_F2 (O_F1+N_F1)
#define N_TOT (O_F2+N_F2)  // 1,092,352 bf16

#define BYTES_BF16 ((size_t)N_TOT*2)
#define OFF_FLOAT  BYTES_BF16              // f32: b1(256) b2(256) bfc1(256) bfc2(1)
#define OFF_FLAG   (OFF_FLOAT + 772*4)     // int out-dtype flag
#define OFF_IDX    (OFF_FLAG + 16)         // int32 idx (131072*3)
#define N_IDX      (131072*3)

static __device__ __forceinline__ f32x4 mfma16(bf16x8 a, bf16x8 b, f32x4 c) {
    return __builtin_amdgcn_mfma_f32_16x16x32_bf16(a, b, c, 0, 0, 0);
}

// ---- normalization, block-range split (no per-element source divergence).
// Blocks [0,1024): idx -> clamped int32 (i64 probe per block).
// Blocks [1024,2048): weights -> bf16 (w2 transposed), biases -> f32 (fp32 probe).
__global__ __launch_bounds__(256)
void convert_all(const void* __restrict__ e0, const void* __restrict__ e1,
                 const void* __restrict__ e2, const void* __restrict__ w1r,
                 const void* __restrict__ b1r, const void* __restrict__ w2r,
                 const void* __restrict__ b2r, const void* __restrict__ f1r,
                 const void* __restrict__ fc1br, const void* __restrict__ f2r,
                 const void* __restrict__ fc2br, const void* __restrict__ idxr,
                 bf16* __restrict__ wsb, float* __restrict__ wsf,
                 int* __restrict__ flagp, int* __restrict__ idx32)
{
    __shared__ int sF;
    const int tid = threadIdx.x;
    const int bid = blockIdx.x;
    if (tid == 0) sF = 0;
    __syncthreads();

    if (bid < 1024) {
        // i64 probe: int64 index buffers (values < 2^31) have all-zero odd words
        if (((const uint32*)idxr)[tid * 2 + 1] != 0) atomicOr(&sF, 1);
        __syncthreads();
        const bool i64 = (sF == 0);
        for (unsigned k = bid * 256u + tid; k < N_IDX; k += 1024u * 256u) {
            long long v = i64 ? ((const long long*)idxr)[k]
                              : (long long)((const int*)idxr)[k];
            unsigned m = k % 3u;
            long long dim = (m == 0 ? 339 : (m == 1 ? 5825 : 64));
            v = v < 0 ? 0 : (v >= dim ? dim - 1 : v);
            idx32[k] = (int)v;
        }
    } else {
        // fp32 probe: low-16-of-word as bf16 with exp>126 impossible for |w1|<=0.37
        if (tid < 64) {
            uint32 e = (((const uint32*)w1r)[tid] >> 7) & 0xffu;
            if (e > 126u) atomicOr(&sF, 1);
        }
        __syncthreads();
        const bool fp32 = (sF != 0);
        if (bid == 1024 && tid == 0) *flagp = fp32 ? 1 : 0;
        for (unsigned i = (bid - 1024) * 256u + tid; i < N_TOT + 769u; i += 1024u * 256u) {
            if (i < N_TOT) {
                const void* src; unsigned off;
                if (i < O_E1)      { src = e0;  off = i; }
                else if (i < O_E2) { src = e1;  off = i - O_E1; }
                else if (i < O_W1) { src = e2;  off = i - O_E2; }
                else if (i < O_W2) { src = w1r; off = i - O_W1; }
                else if (i < O_F1) {                    // w2t[d][m*256+c] = w2[d][c][m]
                    unsigned l = i - O_W2;
                    unsigned d = l / 768u, r = l - d * 768u;
                    unsigned m = r >> 8, c = r & 255u;
                    src = w2r; off = d * 768u + c * 3u + m;
                }
                else if (i < O_F2) { src = f1r; off = i - O_F1; }
                else               { src = f2r; off = i - O_F2; }
                wsb[i] = fp32 ? (bf16)((const float*)src)[off] : ((const bf16*)src)[off];
            } else {
                unsigned j = i - N_TOT;
                const void* src; unsigned off;
                if (j < 256u)      { src = b1r;   off = j; }
                else if (j < 512u) { src = b2r;   off = j - 256u; }
                else if (j < 768u) { src = fc1br; off = j - 512u; }
                else               { src = fc2br; off = 0; }
                wsf[j] = fp32 ? ((const float*)src)[off] : (float)((const bf16*)src)[off];
            }
        }
    }
}

// ---- fused forward. 32 batch rows/block, 25.8 KB LDS, 128-reg cap -> 4 blocks/CU.
__global__ __launch_bounds__(256, 4)
void costco_fused(const bf16* __restrict__ wsb, const float* __restrict__ wsf,
                  const int* __restrict__ flagp, const int* __restrict__ idx32,
                  void* __restrict__ out)
{
    __shared__ alignas(16) bf16 sX[BT * 136];   // gathered x_m rows, 8.7 KB
    __shared__ alignas(16) bf16 sH1[BT * 264];  // h1_m / h2, 16.9 KB
    __shared__ float sRed[BT];

    const bf16* w1   = wsb + O_W1;
    const bf16* w2t  = wsb + O_W2;
    const bf16* wfc1 = wsb + O_F1;
    const bf16* wfc2 = wsb + O_F2;
    const float* fb1  = wsf;
    const float* fb2  = wsf + 256;
    const float* fbc1 = wsf + 512;
    const float  bfc2v = wsf[768];
    const int fp32out = *flagp;

    const int tid  = threadIdx.x;
    const int wave = tid >> 6;
    const int lane = tid & 63;
    const int quad = lane >> 4;
    const int l15  = lane & 15;
    const int bbase = blockIdx.x * BT;

    // 8 threads/row; each thread copies 16 elems (2 x uint4 of 8 bf16) at seg*16
    auto do_gather = [&](int m) {
        const int row = tid >> 3;
        const int seg = tid & 7;
        int ix = idx32[(bbase + row) * 3 + m];
        const bf16* src = wsb + (m == 0 ? O_E0 : (m == 1 ? O_E1 : O_E2))
                          + (size_t)ix * 128 + seg * 16;
        const uint4* s4 = reinterpret_cast<const uint4*>(src);
        uint4* d4 = reinterpret_cast<uint4*>(&sX[row * 136 + seg * 16]);
        d4[0] = s4[0];
        d4[1] = s4[1];
    };

    if (tid < BT) sRed[tid] = bfc2v;
    do_gather(0);
    __syncthreads();

    const f32x4 zero4 = {0.f, 0.f, 0.f, 0.f};
    f32x4 acc2[2][4];
    #pragma unroll
    for (int i = 0; i < 2; ++i)
        #pragma unroll
        for (int j = 0; j < 4; ++j) acc2[i][j] = zero4;

    for (int m = 0; m < 3; ++m) {
        // Stage A: h1_m = relu(x_m W1^T + b1). A=w1 rows c, B=x rows b.
        // D rows=c (4 contiguous per lane) -> vectorized b64 writes to sH1[b][c].
        #pragma unroll
        for (int mtl = 0; mtl < 4; ++mtl) {
            int mt = wave * 4 + mtl;              // c-tile 0..15
            int c  = mt * 16 + l15;
            bf16x8 aw[4];
            #pragma unroll
            for (int ks = 0; ks < 4; ++ks)
                aw[ks] = *reinterpret_cast<const bf16x8*>(w1 + c * 128 + ks * 32 + quad * 8);
            const float4 bv = *reinterpret_cast<const float4*>(fb1 + mt * 16 + quad * 4);
            #pragma unroll
            for (int nt = 0; nt < 2; ++nt) {
                f32x4 acc = zero4;
                #pragma unroll
                for (int ks = 0; ks < 4; ++ks) {
                    bf16x8 xb = *reinterpret_cast<const bf16x8*>(
                        &sX[(nt * 16 + l15) * 136 + ks * 32 + quad * 8]);
                    acc = mfma16(aw[ks], xb, acc);
                }
                bf16x4 hv;
                hv[0] = (bf16)fmaxf(acc[0] + bv.x, 0.f);
                hv[1] = (bf16)fmaxf(acc[1] + bv.y, 0.f);
                hv[2] = (bf16)fmaxf(acc[2] + bv.z, 0.f);
                hv[3] = (bf16)fmaxf(acc[3] + bv.w, 0.f);
                *reinterpret_cast<bf16x4*>(
                    &sH1[(nt * 16 + l15) * 264 + mt * 16 + quad * 4]) = hv;
            }
        }
        __syncthreads();
        if (m < 2) do_gather(m + 1);   // overlaps stage B

        // Stage B: acc2 += h1_m (32x256) . w2t_m^T, waves split N(d)
        #pragma unroll
        for (int ks = 0; ks < 8; ++ks) {
            bf16x8 af[2], bfr[4];
            #pragma unroll
            for (int mt = 0; mt < 2; ++mt)
                af[mt] = *reinterpret_cast<const bf16x8*>(
                    &sH1[(mt * 16 + l15) * 264 + ks * 32 + quad * 8]);
            #pragma unroll
            for (int nt = 0; nt < 4; ++nt) {
                int d = wave * 64 + nt * 16 + l15;
                bfr[nt] = *reinterpret_cast<const bf16x8*>(
                    w2t + d * 768 + m * 256 + ks * 32 + quad * 8);
            }
            #pragma unroll
            for (int mt = 0; mt < 2; ++mt)
                #pragma unroll
                for (int nt = 0; nt < 4; ++nt)
                    acc2[mt][nt] = mfma16(af[mt], bfr[nt], acc2[mt][nt]);
        }
        __syncthreads();
    }

    // h2 epilogue: bias+relu -> sH1 reused as sH2[b][d]
    #pragma unroll
    for (int nt = 0; nt < 4; ++nt) {
        int d = wave * 64 + nt * 16 + l15;
        float b2v = fb2[d];
        #pragma unroll
        for (int mt = 0; mt < 2; ++mt)
            #pragma unroll
            for (int r = 0; r < 4; ++r) {
                int b = mt * 16 + quad * 4 + r;
                sH1[b * 264 + d] = (bf16)fmaxf(acc2[mt][nt][r] + b2v, 0.f);
            }
    }
    __syncthreads();

    // Stage C: h3 = relu(h2 Wfc1^T + bfc1), waves split N(e)
    f32x4 acc3[2][4];
    #pragma unroll
    for (int i = 0; i < 2; ++i)
        #pragma unroll
        for (int j = 0; j < 4; ++j) acc3[i][j] = zero4;
    #pragma unroll
    for (int ks = 0; ks < 8; ++ks) {
        bf16x8 af[2], bfr[4];
        #pragma unroll
        for (int mt = 0; mt < 2; ++mt)
            af[mt] = *reinterpret_cast<const bf16x8*>(
                &sH1[(mt * 16 + l15) * 264 + ks * 32 + quad * 8]);
        #pragma unroll
        for (int nt = 0; nt < 4; ++nt) {
            int e = wave * 64 + nt * 16 + l15;
            bfr[nt] = *reinterpret_cast<const bf16x8*>(wfc1 + e * 256 + ks * 32 + quad * 8);
        }
        #pragma unroll
        for (int mt = 0; mt < 2; ++mt)
            #pragma unroll
            for (int nt = 0; nt < 4; ++nt)
                acc3[mt][nt] = mfma16(af[mt], bfr[nt], acc3[mt][nt]);
    }

    // Stage D: out = relu(h3 . wfc2 + bfc2)
    float wv[4], bc[4];
    #pragma unroll
    for (int nt = 0; nt < 4; ++nt) {
        int e = wave * 64 + nt * 16 + l15;
        wv[nt] = (float)wfc2[e];
        bc[nt] = fbc1[e];
    }
    #pragma unroll
    for (int mt = 0; mt < 2; ++mt)
        #pragma unroll
        for (int r = 0; r < 4; ++r) {
            float p = 0.f;
            #pragma unroll
            for (int nt = 0; nt < 4; ++nt) {
                float h = acc3[mt][nt][r] + bc[nt];
                p += fmaxf(h, 0.f) * wv[nt];
            }
            p += __shfl_xor(p, 1, 64);
            p += __shfl_xor(p, 2, 64);
            p += __shfl_xor(p, 4, 64);
            p += __shfl_xor(p, 8, 64);
            if (l15 == 0) atomicAdd(&sRed[mt * 16 + quad * 4 + r], p);
        }
    __syncthreads();

    if (tid < BT) {
        float v = fmaxf(sRed[tid], 0.f);
        if (fp32out) ((float*)out)[bbase + tid] = v;
        else         ((bf16*)out)[bbase + tid] = (bf16)v;
    }
}

extern "C" void kernel_launch(void* const* d_in, const int* in_sizes, int n_in,
                              void* d_out, int out_size, void* d_ws, size_t ws_size,
                              hipStream_t stream) {
    char* ws = (char*)d_ws;
    bf16*  wsb   = (bf16*)ws;
    float* wsf   = (float*)(ws + OFF_FLOAT);
    int*   flagp = (int*)(ws + OFF_FLAG);
    int*   idx32 = (int*)(ws + OFF_IDX);

    hipLaunchKernelGGL(convert_all, dim3(2048), dim3(256), 0, stream,
                       d_in[1], d_in[2], d_in[3], d_in[4], d_in[5], d_in[6],
                       d_in[7], d_in[8], d_in[9], d_in[10], d_in[11], d_in[0],
                       wsb, wsf, flagp, idx32);

    const int B = 131072;
    hipLaunchKernelGGL(costco_fused, dim3(B / BT), dim3(256), 0, stream,
                       wsb, wsf, flagp, idx32, d_out);
}

// Round 7
// 165.907 us; speedup vs baseline: 2.6229x; 2.6229x over previous
//
#include <hip/hip_runtime.h>

typedef __bf16 bf16;
typedef __bf16 bf16x4 __attribute__((ext_vector_type(4)));
typedef __bf16 bf16x8 __attribute__((ext_vector_type(8)));
typedef float  f32x4  __attribute__((ext_vector_type(4)));
typedef unsigned int uint32;

#define BT 64

// ---- bf16 workspace layout (element offsets) ----
#define N_E0 (339*128)
#define N_E1 (5825*128)
#define N_E2 (64*128)
#define N_W1 (256*128)
#define N_W2 (256*768)
#define N_F1 (256*256)
#define N_F2 256
#define O_E0 0
#define O_E1 (O_E0+N_E0)
#define O_E2 (O_E1+N_E1)
#define O_W1 (O_E2+N_E2)
#define O_W2 (O_W1+N_W1)   // w2 TRANSPOSED: [d][m*256+c]
#define O_F1 (O_W2+N_W2)
#define O_F2 (O_F1+N_F1)
#define N_TOT (O_F2+N_F2)  // 1,092,352 bf16

#define BYTES_BF16 ((size_t)N_TOT*2)
#define OFF_FLOAT  BYTES_BF16              // f32: b1(256) b2(256) bfc1(256) bfc2(1)
#define OFF_FLAG   (OFF_FLOAT + 772*4)
#define OFF_IDX    (OFF_FLAG + 16)         // int32 idx (131072*3)
#define N_IDX      (131072*3)
#define OFF_Q      (OFF_IDX + (size_t)N_IDX*4)

// Q tables (bf16): Q_m[i][d], 6228 rows total -> 3.19 MB (L2-resident)
#define QB0 0
#define QB1 (339*256)
#define QB2 (QB1 + 5825*256)

static __device__ __forceinline__ f32x4 mfma16(bf16x8 a, bf16x8 b, f32x4 c) {
    return __builtin_amdgcn_mfma_f32_16x16x32_bf16(a, b, c, 0, 0, 0);
}

// ---- normalization. Block ranges: [0,256) idx; [256,768) straight-copy;
// [768,1008) w2-transpose; 1008 biases+flag. Probes per block (deterministic).
__global__ __launch_bounds__(256)
void convert_all(const void* __restrict__ e0, const void* __restrict__ e1,
                 const void* __restrict__ e2, const void* __restrict__ w1r,
                 const void* __restrict__ b1r, const void* __restrict__ w2r,
                 const void* __restrict__ b2r, const void* __restrict__ f1r,
                 const void* __restrict__ fc1br, const void* __restrict__ f2r,
                 const void* __restrict__ fc2br, const void* __restrict__ idxr,
                 bf16* __restrict__ wsb, float* __restrict__ wsf,
                 int* __restrict__ flagp, int* __restrict__ idx32)
{
    __shared__ int sF;
    const int tid = threadIdx.x;
    const int bid = blockIdx.x;
    if (tid == 0) sF = 0;
    __syncthreads();

    if (bid < 256) {
        // i64 probe: int64 index buffers (values < 2^31) have all-zero odd words
        if (((const uint32*)idxr)[tid * 2 + 1] != 0) atomicOr(&sF, 1);
        __syncthreads();
        const bool i64 = (sF == 0);
        #pragma unroll
        for (int it = 0; it < 6; ++it) {
            int k = bid * 1536 + it * 256 + tid;
            if (k < N_IDX) {
                long long v = i64 ? ((const long long*)idxr)[k]
                                  : (long long)((const int*)idxr)[k];
                int m = k - (k / 3) * 3;
                long long dim = (m == 0 ? 339 : (m == 1 ? 5825 : 64));
                v = v < 0 ? 0 : (v >= dim ? dim - 1 : v);
                idx32[k] = (int)v;
            }
        }
        return;
    }

    // fp32 probe: low 16 bits of word as bf16 with exp>126 impossible for |w1|<=0.37
    if (tid < 64) {
        uint32 e = (((const uint32*)w1r)[tid] >> 7) & 0xffu;
        if (e > 126u) atomicOr(&sF, 1);
    }
    __syncthreads();
    const bool fp32 = (sF != 0);

    if (bid < 768) {
        // straight-copy: [0,O_W2) = e0|e1|e2|w1 and [O_F1,N_TOT) = f1|f2, vec4
        const unsigned n4 = (O_W2 + (N_TOT - O_F1)) / 4;
        for (unsigned u = (bid - 256) * 256u + tid; u < n4; u += 512u * 256u) {
            unsigned e = u * 4, dst = e;
            const void* src; unsigned off;
            if (e < O_W2) {
                if (e < O_E1)      { src = e0;  off = e; }
                else if (e < O_E2) { src = e1;  off = e - O_E1; }
                else if (e < O_W1) { src = e2;  off = e - O_E2; }
                else               { src = w1r; off = e - O_W1; }
            } else {
                dst = O_F1 + (e - O_W2);
                if (dst < O_F2) { src = f1r; off = dst - O_F1; }
                else            { src = f2r; off = dst - O_F2; }
            }
            if (fp32) {
                float4 v = *(const float4*)((const float*)src + off);
                bf16x4 o; o[0]=(bf16)v.x; o[1]=(bf16)v.y; o[2]=(bf16)v.z; o[3]=(bf16)v.w;
                *(bf16x4*)(wsb + dst) = o;
            } else {
                *(uint2*)(wsb + dst) = *(const uint2*)((const bf16*)src + off);
            }
        }
    } else if (bid < 1008) {
        // w2t[d][m*256+c] = w2[d][c][m]
        for (unsigned i = (bid - 768) * 256u + tid; i < (unsigned)N_W2; i += 240u * 256u) {
            unsigned d = i / 768u, r = i - d * 768u;
            unsigned m = r >> 8, c = r & 255u;
            unsigned off = d * 768u + c * 3u + m;
            wsb[O_W2 + i] = fp32 ? (bf16)((const float*)w2r)[off] : ((const bf16*)w2r)[off];
        }
    } else {
        if (tid == 0) *flagp = fp32 ? 1 : 0;
        #pragma unroll
        for (int it = 0; it < 4; ++it) {
            int j = it * 256 + tid;
            if (j < 769) {
                const void* src; int off;
                if (j < 256)      { src = b1r;   off = j; }
                else if (j < 512) { src = b2r;   off = j - 256; }
                else if (j < 768) { src = fc1br; off = j - 512; }
                else              { src = fc2br; off = 0; }
                wsf[j] = fp32 ? ((const float*)src)[off] : (float)((const bf16*)src)[off];
            }
        }
    }
}

// ---- build Q tables: Q_m[i][d] = sum_c relu(<emb_m[i],w1[c]>+b1[c]) * w2t[d][m*256+c]
// 99 blocks x 64 table rows. Runs once; tiny (1.2 GF).
__global__ __launch_bounds__(256, 2)
void build_q(const bf16* __restrict__ wsb, const float* __restrict__ wsf,
             bf16* __restrict__ Qt)
{
    __shared__ alignas(16) bf16 sX[64 * 136];
    __shared__ alignas(16) bf16 sPE[64 * 264];

    const int tid  = threadIdx.x;
    const int wave = tid >> 6;
    const int lane = tid & 63;
    const int quad = lane >> 4;
    const int l15  = lane & 15;
    const int bid  = blockIdx.x;

    int m, row0, dim, embBase, qBase;
    if (bid < 6)       { m = 0; row0 = bid * 64;        dim = 339;  embBase = O_E0; qBase = QB0; }
    else if (bid < 98) { m = 1; row0 = (bid - 6) * 64;  dim = 5825; embBase = O_E1; qBase = QB1; }
    else               { m = 2; row0 = 0;               dim = 64;   embBase = O_E2; qBase = QB2; }

    const bf16* w1  = wsb + O_W1;
    const bf16* w2t = wsb + O_W2;
    const float* fb1 = wsf;

    // load 64 emb rows (clamped) into sX
    {
        int row = tid >> 2, seg = tid & 3;
        int r = row0 + row; r = r >= dim ? dim - 1 : r;
        const uint4* s4 = (const uint4*)(wsb + embBase + (size_t)r * 128 + seg * 32);
        uint4* d4 = (uint4*)(&sX[row * 136 + seg * 32]);
        #pragma unroll
        for (int u = 0; u < 4; ++u) d4[u] = s4[u];
    }
    __syncthreads();

    const f32x4 zero4 = {0.f, 0.f, 0.f, 0.f};

    // PE tile: A=w1 rows c (M), B=sX rows (N). D row=c, col=table-row.
    #pragma unroll
    for (int mtl = 0; mtl < 4; ++mtl) {
        int mt = wave * 4 + mtl;
        int c  = mt * 16 + l15;
        bf16x8 aw[4];
        #pragma unroll
        for (int ks = 0; ks < 4; ++ks)
            aw[ks] = *(const bf16x8*)(w1 + c * 128 + ks * 32 + quad * 8);
        const float4 bv = *(const float4*)(fb1 + mt * 16 + quad * 4);
        #pragma unroll
        for (int nt = 0; nt < 4; ++nt) {
            f32x4 acc = zero4;
            #pragma unroll
            for (int ks = 0; ks < 4; ++ks) {
                bf16x8 xb = *(const bf16x8*)(&sX[(nt * 16 + l15) * 136 + ks * 32 + quad * 8]);
                acc = mfma16(aw[ks], xb, acc);
            }
            bf16x4 hv;
            hv[0] = (bf16)fmaxf(acc[0] + bv.x, 0.f);
            hv[1] = (bf16)fmaxf(acc[1] + bv.y, 0.f);
            hv[2] = (bf16)fmaxf(acc[2] + bv.z, 0.f);
            hv[3] = (bf16)fmaxf(acc[3] + bv.w, 0.f);
            *(bf16x4*)(&sPE[(nt * 16 + l15) * 264 + mt * 16 + quad * 4]) = hv;
        }
    }
    __syncthreads();

    // Q tile: A=sPE rows (table rows, M), B=w2t rows d (N). No bias, NO relu.
    f32x4 acc2[4][4];
    #pragma unroll
    for (int i = 0; i < 4; ++i)
        #pragma unroll
        for (int j = 0; j < 4; ++j) acc2[i][j] = zero4;
    #pragma unroll
    for (int ks = 0; ks < 8; ++ks) {
        bf16x8 af[4], bfr[4];
        #pragma unroll
        for (int mt = 0; mt < 4; ++mt)
            af[mt] = *(const bf16x8*)(&sPE[(mt * 16 + l15) * 264 + ks * 32 + quad * 8]);
        #pragma unroll
        for (int nt = 0; nt < 4; ++nt) {
            int d = wave * 64 + nt * 16 + l15;
            bfr[nt] = *(const bf16x8*)(w2t + d * 768 + m * 256 + ks * 32 + quad * 8);
        }
        #pragma unroll
        for (int mt = 0; mt < 4; ++mt)
            #pragma unroll
            for (int nt = 0; nt < 4; ++nt)
                acc2[mt][nt] = mfma16(af[mt], bfr[nt], acc2[mt][nt]);
    }
    #pragma unroll
    for (int nt = 0; nt < 4; ++nt) {
        int d = wave * 64 + nt * 16 + l15;
        #pragma unroll
        for (int mt = 0; mt < 4; ++mt)
            #pragma unroll
            for (int r = 0; r < 4; ++r) {
                int rl = mt * 16 + quad * 4 + r;
                if (row0 + rl < dim)
                    Qt[qBase + (size_t)(row0 + rl) * 256 + d] = (bf16)acc2[mt][nt][r];
            }
    }
}

// ---- main: h2 = relu(Q0[i0]+Q1[i1]+Q2[i2]+b2); h3 = relu(h2 Wfc1^T + bfc1);
// ---- out = relu(h3.wfc2 + bfc2). 64 rows/block, 34 KB LDS, only acc3 live.
__global__ __launch_bounds__(256, 3)
void costco_main(const bf16* __restrict__ wsb, const bf16* __restrict__ Qt,
                 const float* __restrict__ wsf, const int* __restrict__ flagp,
                 const int* __restrict__ idx32, void* __restrict__ out)
{
    __shared__ alignas(16) bf16 sH2[BT * 264];
    __shared__ float sRed[BT];

    const bf16* wfc1 = wsb + O_F1;
    const bf16* wfc2 = wsb + O_F2;
    const float* fb2  = wsf + 256;
    const float* fbc1 = wsf + 512;
    const float  bfc2v = wsf[768];
    const int fp32out = *flagp;

    const int tid  = threadIdx.x;
    const int wave = tid >> 6;
    const int lane = tid & 63;
    const int quad = lane >> 4;
    const int l15  = lane & 15;
    const int bbase = blockIdx.x * BT;

    if (tid < BT) sRed[tid] = bfc2v;

    // gather + sum + bias + relu -> sH2 (4 threads/row, 64 elems each)
    {
        const int row = tid >> 2;
        const int seg = tid & 3;
        const int gb  = (bbase + row) * 3;
        int i0 = idx32[gb], i1 = idx32[gb + 1], i2 = idx32[gb + 2];
        const bf16* q0 = Qt + QB0 + (size_t)i0 * 256 + seg * 64;
        const bf16* q1 = Qt + QB1 + (size_t)i1 * 256 + seg * 64;
        const bf16* q2 = Qt + QB2 + (size_t)i2 * 256 + seg * 64;
        #pragma unroll
        for (int s8 = 0; s8 < 8; ++s8) {
            bf16x8 a = *(const bf16x8*)(q0 + s8 * 8);
            bf16x8 b = *(const bf16x8*)(q1 + s8 * 8);
            bf16x8 c = *(const bf16x8*)(q2 + s8 * 8);
            bf16x8 o;
            #pragma unroll
            for (int j = 0; j < 8; ++j) {
                float v = (float)a[j] + (float)b[j] + (float)c[j] + fb2[seg * 64 + s8 * 8 + j];
                o[j] = (bf16)fmaxf(v, 0.f);
            }
            *(bf16x8*)(&sH2[row * 264 + seg * 64 + s8 * 8]) = o;
        }
    }
    __syncthreads();

    const f32x4 zero4 = {0.f, 0.f, 0.f, 0.f};

    // Stage C: h3 = relu(h2 Wfc1^T + bfc1), waves split N(e)
    f32x4 acc3[4][4];
    #pragma unroll
    for (int i = 0; i < 4; ++i)
        #pragma unroll
        for (int j = 0; j < 4; ++j) acc3[i][j] = zero4;
    #pragma unroll
    for (int ks = 0; ks < 8; ++ks) {
        bf16x8 af[4], bfr[4];
        #pragma unroll
        for (int mt = 0; mt < 4; ++mt)
            af[mt] = *(const bf16x8*)(&sH2[(mt * 16 + l15) * 264 + ks * 32 + quad * 8]);
        #pragma unroll
        for (int nt = 0; nt < 4; ++nt) {
            int e = wave * 64 + nt * 16 + l15;
            bfr[nt] = *(const bf16x8*)(wfc1 + e * 256 + ks * 32 + quad * 8);
        }
        #pragma unroll
        for (int mt = 0; mt < 4; ++mt)
            #pragma unroll
            for (int nt = 0; nt < 4; ++nt)
                acc3[mt][nt] = mfma16(af[mt], bfr[nt], acc3[mt][nt]);
    }

    // Stage D
    float wv[4], bc[4];
    #pragma unroll
    for (int nt = 0; nt < 4; ++nt) {
        int e = wave * 64 + nt * 16 + l15;
        wv[nt] = (float)wfc2[e];
        bc[nt] = fbc1[e];
    }
    #pragma unroll
    for (int mt = 0; mt < 4; ++mt)
        #pragma unroll
        for (int r = 0; r < 4; ++r) {
            float p = 0.f;
            #pragma unroll
            for (int nt = 0; nt < 4; ++nt)
                p += fmaxf(acc3[mt][nt][r] + bc[nt], 0.f) * wv[nt];
            p += __shfl_xor(p, 1, 64);
            p += __shfl_xor(p, 2, 64);
            p += __shfl_xor(p, 4, 64);
            p += __shfl_xor(p, 8, 64);
            if (l15 == 0) atomicAdd(&sRed[mt * 16 + quad * 4 + r], p);
        }
    __syncthreads();

    if (tid < BT) {
        float v = fmaxf(sRed[tid], 0.f);
        if (fp32out) ((float*)out)[bbase + tid] = v;
        else         ((bf16*)out)[bbase + tid] = (bf16)v;
    }
}

extern "C" void kernel_launch(void* const* d_in, const int* in_sizes, int n_in,
                              void* d_out, int out_size, void* d_ws, size_t ws_size,
                              hipStream_t stream) {
    char* ws = (char*)d_ws;
    bf16*  wsb   = (bf16*)ws;
    float* wsf   = (float*)(ws + OFF_FLOAT);
    int*   flagp = (int*)(ws + OFF_FLAG);
    int*   idx32 = (int*)(ws + OFF_IDX);
    bf16*  Qt    = (bf16*)(ws + OFF_Q);

    hipLaunchKernelGGL(convert_all, dim3(1009), dim3(256), 0, stream,
                       d_in[1], d_in[2], d_in[3], d_in[4], d_in[5], d_in[6],
                       d_in[7], d_in[8], d_in[9], d_in[10], d_in[11], d_in[0],
                       wsb, wsf, flagp, idx32);

    hipLaunchKernelGGL(build_q, dim3(99), dim3(256), 0, stream, wsb, wsf, Qt);

    const int B = 131072;
    hipLaunchKernelGGL(costco_main, dim3(B / BT), dim3(256), 0, stream,
                       wsb, Qt, wsf, flagp, idx32, d_out);
}